// Round 13
// baseline (334.003 us; speedup 1.0000x reference)
//
#include <hip/hip_runtime.h>
#include <stdint.h>
#include <math.h>

#define Bc   8
#define Nn   38
#define NTc  9
#define ETc  4
#define Rr   416
#define Ee   378
#define Hh   128
#define Ll   12
#define GL   3

typedef __attribute__((ext_vector_type(8))) short s16x8;
typedef __attribute__((ext_vector_type(4))) short s16x4;
typedef __attribute__((ext_vector_type(4))) float f32x4;

// ---------------- workspace layout (bytes) ----------------
// Aliasing is temporally safe: MEP/H0 are dead before SN/TN/SE/TE/PART are written.
static const size_t WS_MN    = 0;         // 15808 -> 15872
static const size_t WS_MEP   = 15872;     // 416*48*64 u8 = 1277952 -> 1293824 (dead after gcn)
static const size_t WS_SN    = 15872;     // 131328   (written by node_st, after gcn)
static const size_t WS_TN    = 147200;    // 131328
static const size_t WS_SE    = 278528;    // 580608
static const size_t WS_TE    = 859136;    // 580608 -> 1439744 (spills into dead H0)
static const size_t WS_PART  = 1439744;   // 512 -> 1440256
static const size_t WS_H0    = 1293824;   // 155648 -> 1449472 (dead after s_kernel)
static const size_t WS_ST    = 1449472;   // 393216 -> 1842688 (bf16 S^T, m pad 64)
static const size_t WS_GWT   = 1842688;   // 294912 -> 2137600 (bf16 gc W^T)
static const size_t WS_NWT   = 2137600;   // 393216 -> 2530816 (bf16 nw1^T)
static const size_t WS_EWT   = 2530816;   // 1179648 -> 3710464 (bf16 ew1^T)
static const size_t WS_ADJP  = 3710464;   // 8*3*48*64 bf16 = 147456 -> 3857920
static const size_t WS_GNB   = 3857920;   // 77824 -> 3935744 (bf16 gnode)
static const size_t WS_GEDGE = 3935744;   // 2322432 -> 6258176 (bf16)

__device__ __forceinline__ unsigned short f2bf(float f) {
  unsigned u = __float_as_uint(f);
  u += 0x7FFFu + ((u >> 16) & 1u);       // RNE
  return (unsigned short)(u >> 16);
}
__device__ __forceinline__ float bf2f(unsigned short h) {
  return __uint_as_float(((unsigned)h) << 16);
}

__device__ __forceinline__ uint8_t mval(const void* src, int i, int mode) {
  if (mode == 0) return ((const int*)src)[i] != 0;
  if (mode == 1) return ((const float*)src)[i] != 0.0f;
  return ((const uint8_t*)src)[i] != 0;
}

// mn u8 [416][38]; mep u8 zero-padded [416][48][64]
__global__ void prep_masks(const void* __restrict__ mn_src, const void* __restrict__ me_src,
                           uint8_t* __restrict__ mn_dst, uint8_t* __restrict__ mep)
{
  __shared__ int s01, sf;
  if (threadIdx.x == 0) { s01 = 1; sf = 1; }
  __syncthreads();
  const uint32_t* p = (const uint32_t*)me_src;
  bool a01 = true, af = true;
  for (int i = threadIdx.x; i < 256; i += blockDim.x) {
    uint32_t v = p[i];
    if (v > 1u) a01 = false;
    if (v != 0u && v != 0x3f800000u) af = false;
  }
  if (!a01) atomicAnd(&s01, 0);
  if (!af)  atomicAnd(&sf, 0);
  __syncthreads();
  const int mode = s01 ? 0 : (sf ? 1 : 2);

  const int n_node = Rr * Nn;                 // 15808
  const int n_pad  = Rr * 48 * 64;            // 1277952
  for (int i = blockIdx.x * blockDim.x + threadIdx.x; i < n_node + n_pad;
       i += gridDim.x * blockDim.x) {
    if (i < n_node) {
      mn_dst[i] = mval(mn_src, i, mode);
    } else {
      int j = i - n_node;
      int m = j & 63;
      int n = (j >> 6) % 48;
      int r = j / (48 * 64);
      uint8_t v = 0;
      if (n < Nn && m < Nn) v = mval(me_src, r * (Nn * Nn) + n * Nn + m, mode);
      mep[j] = v;
    }
  }
}

// weights -> bf16 transposed; adj -> bf16 zero-padded [b][e][48][64]
__global__ void prep_weights(const float* __restrict__ gw, const float* __restrict__ nw1,
                             const float* __restrict__ ew1, const float* __restrict__ adj,
                             unsigned short* __restrict__ gwt, unsigned short* __restrict__ nwt,
                             unsigned short* __restrict__ ewt, unsigned short* __restrict__ adjp)
{
  const int NG  = 9 * 128 * 128;     // 147456
  const int NNw = 12 * 128 * 128;    // 196608
  const int NEw = 12 * 128 * 384;    // 589824
  const int NA  = Bc * GL * 48 * 64; // 73728
  int idx = blockIdx.x * blockDim.x + threadIdx.x;
  if (idx < NG) {
    int k = idx & 127, col = (idx >> 7) & 127, le = idx >> 14;
    gwt[idx] = f2bf(gw[((size_t)le * 128 + k) * 128 + col]);
  } else if (idx < NG + NNw) {
    int j = idx - NG;
    int k = j & 127, col = (j >> 7) & 127, i = j >> 14;
    nwt[j] = f2bf(nw1[((size_t)i * 128 + k) * 128 + col]);
  } else if (idx < NG + NNw + NEw) {
    int j = idx - NG - NNw;
    int k = j % 384; int rem = j / 384;
    int col = rem & 127, i = rem >> 7;
    ewt[j] = f2bf(ew1[((size_t)i * 384 + k) * 128 + col]);
  } else if (idx < NG + NNw + NEw + NA) {
    int j = idx - NG - NNw - NEw;
    int m = j & 63, n = (j >> 6) % 48, be = j / (48 * 64);
    int e = be % GL, b = be / GL;
    unsigned short v = 0;
    if (n < Nn && m < Nn) v = f2bf(adj[((b * ETc + e) * Nn + n) * Nn + m]);
    adjp[j] = v;
  }
}

__global__ void h0_kernel(const float* __restrict__ x, const float* __restrict__ emb_w,
                          float* __restrict__ h0)
{
  int idx = blockIdx.x * blockDim.x + threadIdx.x;
  if (idx >= Bc * Nn * Hh) return;
  int bn = idx >> 7, o = idx & 127;
  float acc = 0.0f;
  #pragma unroll
  for (int i = 0; i < NTc; ++i) acc += x[bn * NTc + i] * emb_w[i * Hh + o];
  h0[idx] = acc;
}

// St[(b*3+e)*128 + col][m(0..63)] = bf16( sum_k h0[b,m,k] * gw[0,e,k,col] ), m>=38 -> 0
__global__ void s_kernel(const float* __restrict__ h0, const float* __restrict__ gw,
                         unsigned short* __restrict__ St)
{
  int idx = blockIdx.x * blockDim.x + threadIdx.x;
  if (idx >= Bc * GL * Hh * 64) return;
  int m = idx & 63;
  int col = (idx >> 6) & 127;
  int t = idx >> 13;
  int e = t % GL, b = t / GL;
  float acc = 0.0f;
  if (m < Nn)
    for (int k = 0; k < Hh; ++k)
      acc += h0[(b * Nn + m) * Hh + k] * gw[((size_t)e * Hh + k) * Hh + col];
  St[idx] = (m < Nn) ? f2bf(acc) : (unsigned short)0;
}

// One block per (b,r), 512 threads = 8 waves, each wave owns ONE 16-col c-tile.
// Same 47.7 KB LDS -> 3 blocks/CU -> 24 waves/CU (was 12): doubles latency hiding
// of the intra-wave GEMM1 -> supT -> GEMM2 chain.
__global__ __launch_bounds__(512, 6)
void gcn_mfma_kernel(const unsigned short* __restrict__ adjp, const uint8_t* __restrict__ mn,
                     const uint8_t* __restrict__ mep, const unsigned short* __restrict__ St,
                     const unsigned short* __restrict__ gwt, const float* __restrict__ gb,
                     const int* __restrict__ isel,
                     unsigned short* __restrict__ gnb, unsigned short* __restrict__ gedge)
{
  __shared__ char smem[47744];
  unsigned short* h_lds  = (unsigned short*)smem;             // 48*128*2 = 12288
  unsigned short* supT   = (unsigned short*)(smem + 12288);   // 128*64*2 = 16384
  unsigned short* am_lds = (unsigned short*)(smem + 28672);   // 3*48*64*2 = 18432
  float*          ge     = (float*)(smem + 47104);            // 512
  unsigned char*  mnu    = (unsigned char*)(smem + 47616);    // 64

  const int tid = threadIdx.x;
  const int b = blockIdx.x / Rr;
  const int r = blockIdx.x - b * Rr;
  const int lane = tid & 63;
  const int wv = tid >> 6;           // 0..7: this wave's c-tile
  const int lo = lane & 15;
  const int q  = lane >> 4;
  const int swz = (lo & 7) << 3;

  // ---- vectorized am staging: 8 elems per chunk ----
  for (int idx = tid; idx < GL * 48 * 8; idx += 512) {
    int e = idx / (48 * 8);
    int rem = idx - e * 384;
    int n = rem >> 3, m0 = (rem & 7) * 8;
    uint64_t mb = *(const uint64_t*)&mep[(size_t)r * 3072 + n * 64 + m0];
    s16x8 av = *(const s16x8*)&adjp[((size_t)(b * GL + e) * 48 + n) * 64 + m0];
    s16x8 o;
    #pragma unroll
    for (int i = 0; i < 8; ++i)
      o[i] = ((mb >> (8 * i)) & 0xffu) ? av[i] : (short)0;
    *(s16x8*)&am_lds[e * 3072 + n * 64 + (m0 ^ ((n & 7) << 3))] = o;
  }
  if (tid < 64) mnu[tid] = (tid < Nn) ? mn[r * Nn + tid] : 0;

  // zero supT logical rows 48..63 (read by GEMM2 A-frags; never written by GEMM1)
  if (tid < 256) {
    int zcol = tid >> 1, zhalf = tid & 1;
    int zsw = (zcol & 7) << 3;
    *(s16x8*)&supT[zcol * 64 + ((48 + 8 * zhalf) ^ zsw)] = (s16x8){0,0,0,0,0,0,0,0};
  }
  __syncthreads();                                           // B1

  // per-lane node-mask dwords for layer-0 A (m = 32*ks + 8*q + 2*d + {0,1})
  uint32_t mkm[2][4];
  #pragma unroll
  for (int ks = 0; ks < 2; ++ks)
    #pragma unroll
    for (int d = 0; d < 4; ++d) {
      int k0 = 32 * ks + 8 * q + 2 * d;
      mkm[ks][d] = (mnu[k0] ? 0x0000FFFFu : 0u) | (mnu[k0 + 1] ? 0xFFFF0000u : 0u);
    }

  f32x4 acc[3];   // [n-tile]: R[c][n], c = 16*wv+4q+j, n = 16*nt+lo

  // ================= layer 0: R = sum_e (mask ⊙ S^T) @ am^T =================
  {
    f32x4 b4 = *(const f32x4*)&gb[16 * wv + 4 * q];
    acc[0] = b4; acc[1] = b4; acc[2] = b4;
  }
  #pragma unroll
  for (int e = 0; e < GL; ++e) {
    const unsigned short* Sb = St + (size_t)(b * GL + e) * 128 * 64;
    #pragma unroll
    for (int ks = 0; ks < 2; ++ks) {
      int m0 = 32 * ks + 8 * q;
      union { s16x8 v; uint32_t u[4]; } A0;
      A0.v = *(const s16x8*)(Sb + (16 * wv + lo) * 64 + m0);
      #pragma unroll
      for (int d = 0; d < 4; ++d) A0.u[d] &= mkm[ks][d];
      #pragma unroll
      for (int nt = 0; nt < 3; ++nt) {
        s16x8 bf = *(const s16x8*)&am_lds[e * 3072 + (16 * nt + lo) * 64 + (m0 ^ swz)];
        acc[nt] = __builtin_amdgcn_mfma_f32_16x16x32_bf16(A0.v, bf, acc[nt], 0, 0, 0);
      }
    }
  }
  // D -> h (relu), b64 writes: row n fixed, 4 consecutive c
  #pragma unroll
  for (int nt = 0; nt < 3; ++nt) {
    int n = 16 * nt + lo;
    int c0 = 16 * wv + 4 * q;
    s16x4 pk;
    #pragma unroll
    for (int j = 0; j < 4; ++j) pk[j] = (short)f2bf(fmaxf(acc[nt][j], 0.0f));
    *(s16x4*)&h_lds[n * 128 + (c0 ^ ((n & 7) << 3))] = pk;
  }
  __syncthreads();                                           // B2: h(0) visible

  // ================= layers 1..2 =================
  #pragma unroll
  for (int l = 1; l < GL; ++l) {
    {
      f32x4 b4 = *(const f32x4*)&gb[l * Hh + 16 * wv + 4 * q];
      acc[0] = b4; acc[1] = b4; acc[2] = b4;
    }

    for (int e = 0; e < GL; ++e) {
      // ---- GEMM1: sup = h @ W[l,e]  (this wave: sup cols [16wv,16wv+16)) ----
      f32x4 sa[3];
      sa[0] = (f32x4){0.f,0.f,0.f,0.f};
      sa[1] = (f32x4){0.f,0.f,0.f,0.f};
      sa[2] = (f32x4){0.f,0.f,0.f,0.f};

      const unsigned short* wb = gwt + (size_t)(l * GL + e) * (Hh * Hh);
      #pragma unroll
      for (int ks = 0; ks < 4; ++ks) {
        int k0 = 8 * q + 32 * ks;
        s16x8 b0 = *(const s16x8*)(wb + (16 * wv + lo) * 128 + k0);
        #pragma unroll
        for (int rt = 0; rt < 3; ++rt) {
          s16x8 a = *(const s16x8*)&h_lds[(lo + 16 * rt) * 128 + (k0 ^ swz)];
          sa[rt] = __builtin_amdgcn_mfma_f32_16x16x32_bf16(a, b0, sa[rt], 0, 0, 0);
        }
      }

      // ---- D1 -> supT[c][m] (b64, intra-wave cols [16wv,16wv+16)) ----
      #pragma unroll
      for (int rt = 0; rt < 3; ++rt) {
        int col = 16 * wv + lo;
        s16x4 pk;
        #pragma unroll
        for (int j = 0; j < 4; ++j) pk[j] = (short)f2bf(sa[rt][j]);
        int k0 = 16 * rt + 4 * q;
        *(s16x4*)&supT[col * 64 + (k0 ^ swz)] = pk;
      }

      // ---- GEMM2 (swapped): R[c][n] += supT[c][m] x am[n][m] ----
      #pragma unroll
      for (int ks = 0; ks < 2; ++ks) {
        int m0 = 32 * ks + 8 * q;
        s16x8 A2 = *(const s16x8*)&supT[(16 * wv + lo) * 64 + (m0 ^ swz)];
        #pragma unroll
        for (int nt = 0; nt < 3; ++nt) {
          s16x8 bf = *(const s16x8*)&am_lds[e * 3072 + (16 * nt + lo) * 64 + (m0 ^ swz)];
          acc[nt] = __builtin_amdgcn_mfma_f32_16x16x32_bf16(A2, bf, acc[nt], 0, 0, 0);
        }
      }
    }

    __syncthreads();   // all waves done reading h(l-1)
    #pragma unroll
    for (int nt = 0; nt < 3; ++nt) {
      int n = 16 * nt + lo;
      int c0 = 16 * wv + 4 * q;
      s16x4 pk;
      #pragma unroll
      for (int j = 0; j < 4; ++j) {
        float v = acc[nt][j];
        if (l < GL - 1) v = fmaxf(v, 0.0f);
        pk[j] = (short)f2bf(v);
      }
      *(s16x4*)&h_lds[n * 128 + (c0 ^ ((n & 7) << 3))] = pk;
    }
    __syncthreads();   // h(l) visible
  }

  // ---- epilogue: graph_emb + outputs ----
  if (tid < 128) {
    float s = 0.0f;
    for (int n = 0; n < Nn; ++n)
      s += bf2f(h_lds[n * 128 + (tid ^ ((n & 7) << 3))]);
    ge[tid] = s;
  }
  __syncthreads();

  if (r < Nn) {
    if (tid < 128) gnb[(size_t)(b * Nn + r) * Hh + tid] = f2bf(ge[tid]);
  } else {
    int ei = r - Nn;
    int i0 = isel[2 * ei], i1 = isel[2 * ei + 1];
    unsigned short* dst = gedge + (size_t)(b * Ee + ei) * 384;
    if (tid < 128) {
      dst[tid]        = h_lds[i0 * 128 + (tid ^ ((i0 & 7) << 3))];
      dst[128 + tid]  = h_lds[i1 * 128 + (tid ^ ((i1 & 7) << 3))];
      dst[256 + tid]  = f2bf(ge[tid]);
    }
  }
}

// ST MLP via MFMA: A [ROWS][IN_W] bf16, wt [12][128][IN_W] bf16, out s/t [12][ROWS][OUT_D]
template<int IN_W, int OUT_D, int ROWS>
__global__ __launch_bounds__(256)
void st_mfma_kernel(const unsigned short* __restrict__ A,
                    const unsigned short* __restrict__ wt,
                    const float* __restrict__ b1,
                    const float* __restrict__ w2,
                    const float* __restrict__ b2,
                    float* __restrict__ s_out, float* __restrict__ t_out)
{
  constexpr int MT = (ROWS + 31) / 32;
  constexpr int OD2 = 2 * OUT_D;
  __shared__ unsigned short hid[32 * 136];
  const int tid = threadIdx.x;
  const int i = blockIdx.x / MT;
  const int mt = blockIdx.x - i * MT;
  const int row0 = mt * 32;
  const int lane = tid & 63, wv = tid >> 6;
  const int lo = lane & 15, q = lane >> 4;

  f32x4 acc[2][2];
  #pragma unroll
  for (int rt = 0; rt < 2; ++rt)
    #pragma unroll
    for (int ci = 0; ci < 2; ++ci)
      acc[rt][ci] = (f32x4){0.f, 0.f, 0.f, 0.f};

  int ra = row0 + lo;       if (ra >= ROWS) ra = 0;
  int rb = row0 + 16 + lo;  if (rb >= ROWS) rb = 0;
  const unsigned short* Ap0 = A + (size_t)ra * IN_W;
  const unsigned short* Ap1 = A + (size_t)rb * IN_W;
  const unsigned short* Bp0 = wt + ((size_t)i * 128 + 32 * wv + lo) * IN_W;
  const unsigned short* Bp1 = wt + ((size_t)i * 128 + 32 * wv + 16 + lo) * IN_W;

  #pragma unroll
  for (int ks = 0; ks < IN_W / 32; ++ks) {
    int k0 = 8 * q + 32 * ks;
    s16x8 a0 = *(const s16x8*)(Ap0 + k0);
    s16x8 a1 = *(const s16x8*)(Ap1 + k0);
    s16x8 b0 = *(const s16x8*)(Bp0 + k0);
    s16x8 b1 = *(const s16x8*)(Bp1 + k0);
    acc[0][0] = __builtin_amdgcn_mfma_f32_16x16x32_bf16(a0, b0, acc[0][0], 0, 0, 0);
    acc[0][1] = __builtin_amdgcn_mfma_f32_16x16x32_bf16(a0, b1, acc[0][1], 0, 0, 0);
    acc[1][0] = __builtin_amdgcn_mfma_f32_16x16x32_bf16(a1, b0, acc[1][0], 0, 0, 0);
    acc[1][1] = __builtin_amdgcn_mfma_f32_16x16x32_bf16(a1, b1, acc[1][1], 0, 0, 0);
  }

  #pragma unroll
  for (int rt = 0; rt < 2; ++rt)
    #pragma unroll
    for (int ci = 0; ci < 2; ++ci) {
      int col = 32 * wv + 16 * ci + lo;
      float bb = b1[i * 128 + col];
      #pragma unroll
      for (int j = 0; j < 4; ++j) {
        int row = 16 * rt + 4 * q + j;
        hid[row * 136 + col] = f2bf(tanhf(acc[rt][ci][j] + bb));
      }
    }
  __syncthreads();

  for (int idx = tid; idx < 32 * OD2; idx += 256) {
    int lr = idx / OD2, c = idx - lr * OD2;
    int gr = row0 + lr;
    if (gr < ROWS) {
      float a = b2[i * OD2 + c];
      for (int k = 0; k < 128; ++k)
        a += bf2f(hid[lr * 136 + k]) * w2[((size_t)i * 128 + k) * OD2 + c];
      if (c < OUT_D) s_out[((size_t)i * ROWS + gr) * OUT_D + c] = 1.0f / (1.0f + expf(-(a + 2.0f)));
      else           t_out[((size_t)i * ROWS + gr) * OUT_D + (c - OUT_D)] = a;
    }
  }
}

// per-element 12-layer fold + partial log-jacobians (8 chunks per b)
__global__ __launch_bounds__(256)
void combine_part(const float* __restrict__ x_deq, const float* __restrict__ adj_deq,
                  const float* __restrict__ sn, const float* __restrict__ tn,
                  const float* __restrict__ se, const float* __restrict__ te,
                  float* __restrict__ out, float* __restrict__ partials)
{
  const int blk = blockIdx.x, tid = threadIdx.x;
  const int b = blk >> 3, ch = blk & 7;
  float ljx = 0.0f, lja = 0.0f;

  for (int j = ch * 256 + tid; j < Nn * NTc; j += 2048) {
    int n = j / NTc, c = j - n * NTc;
    int row = b * Nn + n;
    float v = x_deq[b * (Nn * NTc) + j];
    #pragma unroll
    for (int i = 0; i < Ll; ++i) {
      float s = sn[((size_t)i * (Bc * Nn) + row) * NTc + c];
      float t = tn[((size_t)i * (Bc * Nn) + row) * NTc + c];
      v = v * s + t;
      ljx += logf(fabsf(s) + 1e-20f);
    }
    out[b * (Nn * NTc) + j] = v;
  }

  for (int j = ch * 256 + tid; j < Ee * ETc; j += 2048) {
    int e = j / ETc, c = j - e * ETc;
    int row = b * Ee + e;
    float v = adj_deq[b * (Ee * ETc) + j];
    #pragma unroll
    for (int i = 0; i < Ll; ++i) {
      float s = se[((size_t)i * (Bc * Ee) + row) * ETc + c];
      float t = te[((size_t)i * (Bc * Ee) + row) * ETc + c];
      v = v * s + t;
      lja += logf(fabsf(s) + 1e-20f);
    }
    out[Bc * Nn * NTc + b * (Ee * ETc) + j] = v;
  }

  __shared__ float red[256];
  red[tid] = ljx; __syncthreads();
  for (int st = 128; st > 0; st >>= 1) { if (tid < st) red[tid] += red[tid + st]; __syncthreads(); }
  if (tid == 0) partials[blk] = red[0];
  __syncthreads();
  red[tid] = lja; __syncthreads();
  for (int st = 128; st > 0; st >>= 1) { if (tid < st) red[tid] += red[tid + st]; __syncthreads(); }
  if (tid == 0) partials[64 + blk] = red[0];
}

__global__ void combine_lj(const float* __restrict__ partials, float* __restrict__ out)
{
  int tid = threadIdx.x;
  if (tid < Bc) {
    float sx = 0.0f, sa = 0.0f;
    #pragma unroll
    for (int ch = 0; ch < 8; ++ch) {
      sx += partials[tid * 8 + ch];
      sa += partials[64 + tid * 8 + ch];
    }
    out[Bc * Nn * NTc + Bc * Ee * ETc + tid] = sx;
    out[Bc * Nn * NTc + Bc * Ee * ETc + Bc + tid] = sa;
  }
}

extern "C" void kernel_launch(void* const* d_in, const int* in_sizes, int n_in,
                              void* d_out, int out_size, void* d_ws, size_t ws_size,
                              hipStream_t stream)
{
  const float* x       = (const float*)d_in[0];
  const float* adj     = (const float*)d_in[1];
  const float* x_deq   = (const float*)d_in[2];
  const float* adj_deq = (const float*)d_in[3];
  const void*  mn_src  = d_in[4];
  const void*  me_src  = d_in[5];
  const int*   isel    = (const int*)d_in[6];
  const float* emb_w   = (const float*)d_in[7];
  const float* gw      = (const float*)d_in[8];
  const float* gb      = (const float*)d_in[9];
  const float* nw1     = (const float*)d_in[10];
  const float* nb1     = (const float*)d_in[11];
  const float* nw2     = (const float*)d_in[12];
  const float* nb2     = (const float*)d_in[13];
  const float* ew1     = (const float*)d_in[14];
  const float* eb1     = (const float*)d_in[15];
  const float* ew2     = (const float*)d_in[16];
  const float* eb2     = (const float*)d_in[17];

  char* ws = (char*)d_ws;
  uint8_t* mn            = (uint8_t*)(ws + WS_MN);
  uint8_t* mep           = (uint8_t*)(ws + WS_MEP);
  float* h0              = (float*)(ws + WS_H0);
  unsigned short* St     = (unsigned short*)(ws + WS_ST);
  unsigned short* gwt    = (unsigned short*)(ws + WS_GWT);
  unsigned short* nwt    = (unsigned short*)(ws + WS_NWT);
  unsigned short* ewt    = (unsigned short*)(ws + WS_EWT);
  unsigned short* adjp   = (unsigned short*)(ws + WS_ADJP);
  unsigned short* gnb    = (unsigned short*)(ws + WS_GNB);
  unsigned short* gedge  = (unsigned short*)(ws + WS_GEDGE);
  float* sn              = (float*)(ws + WS_SN);
  float* tn              = (float*)(ws + WS_TN);
  float* se              = (float*)(ws + WS_SE);
  float* te              = (float*)(ws + WS_TE);
  float* partials        = (float*)(ws + WS_PART);

  const int NW_TOT = 9 * 128 * 128 + 12 * 128 * 128 + 12 * 128 * 384 + Bc * GL * 48 * 64;

  prep_masks<<<256, 256, 0, stream>>>(mn_src, me_src, mn, mep);
  prep_weights<<<(NW_TOT + 255) / 256, 256, 0, stream>>>(gw, nw1, ew1, adj, gwt, nwt, ewt, adjp);
  h0_kernel<<<(Bc * Nn * Hh + 255) / 256, 256, 0, stream>>>(x, emb_w, h0);
  s_kernel<<<(Bc * GL * Hh * 64 + 255) / 256, 256, 0, stream>>>(h0, gw, St);
  gcn_mfma_kernel<<<Bc * Rr, 512, 0, stream>>>(adjp, mn, mep, St, gwt, gb, isel, gnb, gedge);
  st_mfma_kernel<128, NTc, Bc * Nn><<<Ll * ((Bc * Nn + 31) / 32), 256, 0, stream>>>(
      gnb, nwt, nb1, nw2, nb2, sn, tn);
  st_mfma_kernel<384, ETc, Bc * Ee><<<Ll * ((Bc * Ee + 31) / 32), 256, 0, stream>>>(
      gedge, ewt, eb1, ew2, eb2, se, te);
  combine_part<<<Bc * 8, 256, 0, stream>>>(x_deq, adj_deq, sn, tn, se, te, (float*)d_out, partials);
  combine_lj<<<1, 64, 0, stream>>>(partials, (float*)d_out);
}

// Round 14
// 290.925 us; speedup vs baseline: 1.1481x; 1.1481x over previous
//
#include <hip/hip_runtime.h>
#include <stdint.h>
#include <math.h>

#define Bc   8
#define Nn   38
#define NTc  9
#define ETc  4
#define Rr   416
#define Ee   378
#define Hh   128
#define Ll   12
#define GL   3

typedef __attribute__((ext_vector_type(8))) short s16x8;
typedef __attribute__((ext_vector_type(4))) short s16x4;
typedef __attribute__((ext_vector_type(4))) float f32x4;

// ---------------- workspace layout (bytes) ----------------
// Aliasing is temporally safe: MEP/H0 are dead before SN/TN/SE/TE/PART are written.
static const size_t WS_MN    = 0;         // 15808 -> 15872
static const size_t WS_MEP   = 15872;     // 416*48*64 u8 = 1277952 -> 1293824 (dead after gcn)
static const size_t WS_SN    = 15872;     // 131328   (written by node_st, after gcn)
static const size_t WS_TN    = 147200;    // 131328
static const size_t WS_SE    = 278528;    // 580608
static const size_t WS_TE    = 859136;    // 580608 -> 1439744 (spills into dead H0)
static const size_t WS_PART  = 1439744;   // 512 -> 1440256
static const size_t WS_H0    = 1293824;   // 155648 -> 1449472 (dead after s_kernel)
static const size_t WS_ST    = 1449472;   // 393216 -> 1842688 (bf16 S^T, m pad 64)
static const size_t WS_GWT   = 1842688;   // 294912 -> 2137600 (bf16 gc W^T)
static const size_t WS_NWT   = 2137600;   // 393216 -> 2530816 (bf16 nw1^T)
static const size_t WS_EWT   = 2530816;   // 1179648 -> 3710464 (bf16 ew1^T)
static const size_t WS_ADJP  = 3710464;   // 8*3*48*64 bf16 = 147456 -> 3857920
static const size_t WS_GNB   = 3857920;   // 77824 -> 3935744 (bf16 gnode)
static const size_t WS_GEDGE = 3935744;   // 2322432 -> 6258176 (bf16)

__device__ __forceinline__ unsigned short f2bf(float f) {
  unsigned u = __float_as_uint(f);
  u += 0x7FFFu + ((u >> 16) & 1u);       // RNE
  return (unsigned short)(u >> 16);
}
__device__ __forceinline__ float bf2f(unsigned short h) {
  return __uint_as_float(((unsigned)h) << 16);
}

__device__ __forceinline__ uint8_t mval(const void* src, int i, int mode) {
  if (mode == 0) return ((const int*)src)[i] != 0;
  if (mode == 1) return ((const float*)src)[i] != 0.0f;
  return ((const uint8_t*)src)[i] != 0;
}

// mn u8 [416][38]; mep u8 zero-padded [416][48][64]
__global__ void prep_masks(const void* __restrict__ mn_src, const void* __restrict__ me_src,
                           uint8_t* __restrict__ mn_dst, uint8_t* __restrict__ mep)
{
  __shared__ int s01, sf;
  if (threadIdx.x == 0) { s01 = 1; sf = 1; }
  __syncthreads();
  const uint32_t* p = (const uint32_t*)me_src;
  bool a01 = true, af = true;
  for (int i = threadIdx.x; i < 256; i += blockDim.x) {
    uint32_t v = p[i];
    if (v > 1u) a01 = false;
    if (v != 0u && v != 0x3f800000u) af = false;
  }
  if (!a01) atomicAnd(&s01, 0);
  if (!af)  atomicAnd(&sf, 0);
  __syncthreads();
  const int mode = s01 ? 0 : (sf ? 1 : 2);

  const int n_node = Rr * Nn;                 // 15808
  const int n_pad  = Rr * 48 * 64;            // 1277952
  for (int i = blockIdx.x * blockDim.x + threadIdx.x; i < n_node + n_pad;
       i += gridDim.x * blockDim.x) {
    if (i < n_node) {
      mn_dst[i] = mval(mn_src, i, mode);
    } else {
      int j = i - n_node;
      int m = j & 63;
      int n = (j >> 6) % 48;
      int r = j / (48 * 64);
      uint8_t v = 0;
      if (n < Nn && m < Nn) v = mval(me_src, r * (Nn * Nn) + n * Nn + m, mode);
      mep[j] = v;
    }
  }
}

// weights -> bf16 transposed; adj -> bf16 zero-padded [b][e][48][64]
__global__ void prep_weights(const float* __restrict__ gw, const float* __restrict__ nw1,
                             const float* __restrict__ ew1, const float* __restrict__ adj,
                             unsigned short* __restrict__ gwt, unsigned short* __restrict__ nwt,
                             unsigned short* __restrict__ ewt, unsigned short* __restrict__ adjp)
{
  const int NG  = 9 * 128 * 128;     // 147456
  const int NNw = 12 * 128 * 128;    // 196608
  const int NEw = 12 * 128 * 384;    // 589824
  const int NA  = Bc * GL * 48 * 64; // 73728
  int idx = blockIdx.x * blockDim.x + threadIdx.x;
  if (idx < NG) {
    int k = idx & 127, col = (idx >> 7) & 127, le = idx >> 14;
    gwt[idx] = f2bf(gw[((size_t)le * 128 + k) * 128 + col]);
  } else if (idx < NG + NNw) {
    int j = idx - NG;
    int k = j & 127, col = (j >> 7) & 127, i = j >> 14;
    nwt[j] = f2bf(nw1[((size_t)i * 128 + k) * 128 + col]);
  } else if (idx < NG + NNw + NEw) {
    int j = idx - NG - NNw;
    int k = j % 384; int rem = j / 384;
    int col = rem & 127, i = rem >> 7;
    ewt[j] = f2bf(ew1[((size_t)i * 384 + k) * 128 + col]);
  } else if (idx < NG + NNw + NEw + NA) {
    int j = idx - NG - NNw - NEw;
    int m = j & 63, n = (j >> 6) % 48, be = j / (48 * 64);
    int e = be % GL, b = be / GL;
    unsigned short v = 0;
    if (n < Nn && m < Nn) v = f2bf(adj[((b * ETc + e) * Nn + n) * Nn + m]);
    adjp[j] = v;
  }
}

__global__ void h0_kernel(const float* __restrict__ x, const float* __restrict__ emb_w,
                          float* __restrict__ h0)
{
  int idx = blockIdx.x * blockDim.x + threadIdx.x;
  if (idx >= Bc * Nn * Hh) return;
  int bn = idx >> 7, o = idx & 127;
  float acc = 0.0f;
  #pragma unroll
  for (int i = 0; i < NTc; ++i) acc += x[bn * NTc + i] * emb_w[i * Hh + o];
  h0[idx] = acc;
}

// St[(b*3+e)*128 + col][m(0..63)] = bf16( sum_k h0[b,m,k] * gw[0,e,k,col] ), m>=38 -> 0
__global__ void s_kernel(const float* __restrict__ h0, const float* __restrict__ gw,
                         unsigned short* __restrict__ St)
{
  int idx = blockIdx.x * blockDim.x + threadIdx.x;
  if (idx >= Bc * GL * Hh * 64) return;
  int m = idx & 63;
  int col = (idx >> 6) & 127;
  int t = idx >> 13;
  int e = t % GL, b = t / GL;
  float acc = 0.0f;
  if (m < Nn)
    for (int k = 0; k < Hh; ++k)
      acc += h0[(b * Nn + m) * Hh + k] * gw[((size_t)e * Hh + k) * Hh + col];
  St[idx] = (m < Nn) ? f2bf(acc) : (unsigned short)0;
}

// One block per (b,r), 512 threads = 8 waves, each wave owns ONE 16-col c-tile.
// __launch_bounds__(512, 3): 2nd arg is MIN BLOCKS/CU (CUDA semantics — round-13
// measured VGPR=40 proves it; 6 here caused 12 waves/SIMD target -> 42-VGPR cap
// -> 271 MB spill traffic). 3 blocks x 8 waves / 4 SIMD = 6 waves/SIMD -> 85-VGPR
// cap, kernel needs ~60 -> no spill, 24 waves/CU latency hiding.
__global__ __launch_bounds__(512, 3)
void gcn_mfma_kernel(const unsigned short* __restrict__ adjp, const uint8_t* __restrict__ mn,
                     const uint8_t* __restrict__ mep, const unsigned short* __restrict__ St,
                     const unsigned short* __restrict__ gwt, const float* __restrict__ gb,
                     const int* __restrict__ isel,
                     unsigned short* __restrict__ gnb, unsigned short* __restrict__ gedge)
{
  __shared__ char smem[47744];
  unsigned short* h_lds  = (unsigned short*)smem;             // 48*128*2 = 12288
  unsigned short* supT   = (unsigned short*)(smem + 12288);   // 128*64*2 = 16384
  unsigned short* am_lds = (unsigned short*)(smem + 28672);   // 3*48*64*2 = 18432
  float*          ge     = (float*)(smem + 47104);            // 512
  unsigned char*  mnu    = (unsigned char*)(smem + 47616);    // 64

  const int tid = threadIdx.x;
  const int b = blockIdx.x / Rr;
  const int r = blockIdx.x - b * Rr;
  const int lane = tid & 63;
  const int wv = tid >> 6;           // 0..7: this wave's c-tile
  const int lo = lane & 15;
  const int q  = lane >> 4;
  const int swz = (lo & 7) << 3;

  // ---- vectorized am staging: 8 elems per chunk ----
  for (int idx = tid; idx < GL * 48 * 8; idx += 512) {
    int e = idx / (48 * 8);
    int rem = idx - e * 384;
    int n = rem >> 3, m0 = (rem & 7) * 8;
    uint64_t mb = *(const uint64_t*)&mep[(size_t)r * 3072 + n * 64 + m0];
    s16x8 av = *(const s16x8*)&adjp[((size_t)(b * GL + e) * 48 + n) * 64 + m0];
    s16x8 o;
    #pragma unroll
    for (int i = 0; i < 8; ++i)
      o[i] = ((mb >> (8 * i)) & 0xffu) ? av[i] : (short)0;
    *(s16x8*)&am_lds[e * 3072 + n * 64 + (m0 ^ ((n & 7) << 3))] = o;
  }
  if (tid < 64) mnu[tid] = (tid < Nn) ? mn[r * Nn + tid] : 0;

  // zero supT logical rows 48..63 (read by GEMM2 A-frags; never written by GEMM1)
  if (tid < 256) {
    int zcol = tid >> 1, zhalf = tid & 1;
    int zsw = (zcol & 7) << 3;
    *(s16x8*)&supT[zcol * 64 + ((48 + 8 * zhalf) ^ zsw)] = (s16x8){0,0,0,0,0,0,0,0};
  }
  __syncthreads();                                           // B1

  // per-lane node-mask dwords for layer-0 A (m = 32*ks + 8*q + 2*d + {0,1})
  uint32_t mkm[2][4];
  #pragma unroll
  for (int ks = 0; ks < 2; ++ks)
    #pragma unroll
    for (int d = 0; d < 4; ++d) {
      int k0 = 32 * ks + 8 * q + 2 * d;
      mkm[ks][d] = (mnu[k0] ? 0x0000FFFFu : 0u) | (mnu[k0 + 1] ? 0xFFFF0000u : 0u);
    }

  f32x4 acc[3];   // [n-tile]: R[c][n], c = 16*wv+4q+j, n = 16*nt+lo

  // ================= layer 0: R = sum_e (mask ⊙ S^T) @ am^T =================
  {
    f32x4 b4 = *(const f32x4*)&gb[16 * wv + 4 * q];
    acc[0] = b4; acc[1] = b4; acc[2] = b4;
  }
  #pragma unroll
  for (int e = 0; e < GL; ++e) {
    const unsigned short* Sb = St + (size_t)(b * GL + e) * 128 * 64;
    #pragma unroll
    for (int ks = 0; ks < 2; ++ks) {
      int m0 = 32 * ks + 8 * q;
      union { s16x8 v; uint32_t u[4]; } A0;
      A0.v = *(const s16x8*)(Sb + (16 * wv + lo) * 64 + m0);
      #pragma unroll
      for (int d = 0; d < 4; ++d) A0.u[d] &= mkm[ks][d];
      #pragma unroll
      for (int nt = 0; nt < 3; ++nt) {
        s16x8 bf = *(const s16x8*)&am_lds[e * 3072 + (16 * nt + lo) * 64 + (m0 ^ swz)];
        acc[nt] = __builtin_amdgcn_mfma_f32_16x16x32_bf16(A0.v, bf, acc[nt], 0, 0, 0);
      }
    }
  }
  // D -> h (relu), b64 writes: row n fixed, 4 consecutive c
  #pragma unroll
  for (int nt = 0; nt < 3; ++nt) {
    int n = 16 * nt + lo;
    int c0 = 16 * wv + 4 * q;
    s16x4 pk;
    #pragma unroll
    for (int j = 0; j < 4; ++j) pk[j] = (short)f2bf(fmaxf(acc[nt][j], 0.0f));
    *(s16x4*)&h_lds[n * 128 + (c0 ^ ((n & 7) << 3))] = pk;
  }
  __syncthreads();                                           // B2: h(0) visible

  // ================= layers 1..2 =================
  #pragma unroll
  for (int l = 1; l < GL; ++l) {
    {
      f32x4 b4 = *(const f32x4*)&gb[l * Hh + 16 * wv + 4 * q];
      acc[0] = b4; acc[1] = b4; acc[2] = b4;
    }

    for (int e = 0; e < GL; ++e) {
      // ---- GEMM1: sup = h @ W[l,e]  (this wave: sup cols [16wv,16wv+16)) ----
      f32x4 sa[3];
      sa[0] = (f32x4){0.f,0.f,0.f,0.f};
      sa[1] = (f32x4){0.f,0.f,0.f,0.f};
      sa[2] = (f32x4){0.f,0.f,0.f,0.f};

      const unsigned short* wb = gwt + (size_t)(l * GL + e) * (Hh * Hh);
      #pragma unroll
      for (int ks = 0; ks < 4; ++ks) {
        int k0 = 8 * q + 32 * ks;
        s16x8 b0 = *(const s16x8*)(wb + (16 * wv + lo) * 128 + k0);
        #pragma unroll
        for (int rt = 0; rt < 3; ++rt) {
          s16x8 a = *(const s16x8*)&h_lds[(lo + 16 * rt) * 128 + (k0 ^ swz)];
          sa[rt] = __builtin_amdgcn_mfma_f32_16x16x32_bf16(a, b0, sa[rt], 0, 0, 0);
        }
      }

      // ---- D1 -> supT[c][m] (b64, intra-wave cols [16wv,16wv+16)) ----
      #pragma unroll
      for (int rt = 0; rt < 3; ++rt) {
        int col = 16 * wv + lo;
        s16x4 pk;
        #pragma unroll
        for (int j = 0; j < 4; ++j) pk[j] = (short)f2bf(sa[rt][j]);
        int k0 = 16 * rt + 4 * q;
        *(s16x4*)&supT[col * 64 + (k0 ^ swz)] = pk;
      }

      // ---- GEMM2 (swapped): R[c][n] += supT[c][m] x am[n][m] ----
      #pragma unroll
      for (int ks = 0; ks < 2; ++ks) {
        int m0 = 32 * ks + 8 * q;
        s16x8 A2 = *(const s16x8*)&supT[(16 * wv + lo) * 64 + (m0 ^ swz)];
        #pragma unroll
        for (int nt = 0; nt < 3; ++nt) {
          s16x8 bf = *(const s16x8*)&am_lds[e * 3072 + (16 * nt + lo) * 64 + (m0 ^ swz)];
          acc[nt] = __builtin_amdgcn_mfma_f32_16x16x32_bf16(A2, bf, acc[nt], 0, 0, 0);
        }
      }
    }

    __syncthreads();   // all waves done reading h(l-1)
    #pragma unroll
    for (int nt = 0; nt < 3; ++nt) {
      int n = 16 * nt + lo;
      int c0 = 16 * wv + 4 * q;
      s16x4 pk;
      #pragma unroll
      for (int j = 0; j < 4; ++j) {
        float v = acc[nt][j];
        if (l < GL - 1) v = fmaxf(v, 0.0f);
        pk[j] = (short)f2bf(v);
      }
      *(s16x4*)&h_lds[n * 128 + (c0 ^ ((n & 7) << 3))] = pk;
    }
    __syncthreads();   // h(l) visible
  }

  // ---- epilogue: graph_emb + outputs ----
  if (tid < 128) {
    float s = 0.0f;
    for (int n = 0; n < Nn; ++n)
      s += bf2f(h_lds[n * 128 + (tid ^ ((n & 7) << 3))]);
    ge[tid] = s;
  }
  __syncthreads();

  if (r < Nn) {
    if (tid < 128) gnb[(size_t)(b * Nn + r) * Hh + tid] = f2bf(ge[tid]);
  } else {
    int ei = r - Nn;
    int i0 = isel[2 * ei], i1 = isel[2 * ei + 1];
    unsigned short* dst = gedge + (size_t)(b * Ee + ei) * 384;
    if (tid < 128) {
      dst[tid]        = h_lds[i0 * 128 + (tid ^ ((i0 & 7) << 3))];
      dst[128 + tid]  = h_lds[i1 * 128 + (tid ^ ((i1 & 7) << 3))];
      dst[256 + tid]  = f2bf(ge[tid]);
    }
  }
}

// ST MLP via MFMA: A [ROWS][IN_W] bf16, wt [12][128][IN_W] bf16, out s/t [12][ROWS][OUT_D]
template<int IN_W, int OUT_D, int ROWS>
__global__ __launch_bounds__(256)
void st_mfma_kernel(const unsigned short* __restrict__ A,
                    const unsigned short* __restrict__ wt,
                    const float* __restrict__ b1,
                    const float* __restrict__ w2,
                    const float* __restrict__ b2,
                    float* __restrict__ s_out, float* __restrict__ t_out)
{
  constexpr int MT = (ROWS + 31) / 32;
  constexpr int OD2 = 2 * OUT_D;
  __shared__ unsigned short hid[32 * 136];
  const int tid = threadIdx.x;
  const int i = blockIdx.x / MT;
  const int mt = blockIdx.x - i * MT;
  const int row0 = mt * 32;
  const int lane = tid & 63, wv = tid >> 6;
  const int lo = lane & 15, q = lane >> 4;

  f32x4 acc[2][2];
  #pragma unroll
  for (int rt = 0; rt < 2; ++rt)
    #pragma unroll
    for (int ci = 0; ci < 2; ++ci)
      acc[rt][ci] = (f32x4){0.f, 0.f, 0.f, 0.f};

  int ra = row0 + lo;       if (ra >= ROWS) ra = 0;
  int rb = row0 + 16 + lo;  if (rb >= ROWS) rb = 0;
  const unsigned short* Ap0 = A + (size_t)ra * IN_W;
  const unsigned short* Ap1 = A + (size_t)rb * IN_W;
  const unsigned short* Bp0 = wt + ((size_t)i * 128 + 32 * wv + lo) * IN_W;
  const unsigned short* Bp1 = wt + ((size_t)i * 128 + 32 * wv + 16 + lo) * IN_W;

  #pragma unroll
  for (int ks = 0; ks < IN_W / 32; ++ks) {
    int k0 = 8 * q + 32 * ks;
    s16x8 a0 = *(const s16x8*)(Ap0 + k0);
    s16x8 a1 = *(const s16x8*)(Ap1 + k0);
    s16x8 b0 = *(const s16x8*)(Bp0 + k0);
    s16x8 b1 = *(const s16x8*)(Bp1 + k0);
    acc[0][0] = __builtin_amdgcn_mfma_f32_16x16x32_bf16(a0, b0, acc[0][0], 0, 0, 0);
    acc[0][1] = __builtin_amdgcn_mfma_f32_16x16x32_bf16(a0, b1, acc[0][1], 0, 0, 0);
    acc[1][0] = __builtin_amdgcn_mfma_f32_16x16x32_bf16(a1, b0, acc[1][0], 0, 0, 0);
    acc[1][1] = __builtin_amdgcn_mfma_f32_16x16x32_bf16(a1, b1, acc[1][1], 0, 0, 0);
  }

  #pragma unroll
  for (int rt = 0; rt < 2; ++rt)
    #pragma unroll
    for (int ci = 0; ci < 2; ++ci) {
      int col = 32 * wv + 16 * ci + lo;
      float bb = b1[i * 128 + col];
      #pragma unroll
      for (int j = 0; j < 4; ++j) {
        int row = 16 * rt + 4 * q + j;
        hid[row * 136 + col] = f2bf(tanhf(acc[rt][ci][j] + bb));
      }
    }
  __syncthreads();

  for (int idx = tid; idx < 32 * OD2; idx += 256) {
    int lr = idx / OD2, c = idx - lr * OD2;
    int gr = row0 + lr;
    if (gr < ROWS) {
      float a = b2[i * OD2 + c];
      for (int k = 0; k < 128; ++k)
        a += bf2f(hid[lr * 136 + k]) * w2[((size_t)i * 128 + k) * OD2 + c];
      if (c < OUT_D) s_out[((size_t)i * ROWS + gr) * OUT_D + c] = 1.0f / (1.0f + expf(-(a + 2.0f)));
      else           t_out[((size_t)i * ROWS + gr) * OUT_D + (c - OUT_D)] = a;
    }
  }
}

// per-element 12-layer fold + partial log-jacobians (8 chunks per b)
__global__ __launch_bounds__(256)
void combine_part(const float* __restrict__ x_deq, const float* __restrict__ adj_deq,
                  const float* __restrict__ sn, const float* __restrict__ tn,
                  const float* __restrict__ se, const float* __restrict__ te,
                  float* __restrict__ out, float* __restrict__ partials)
{
  const int blk = blockIdx.x, tid = threadIdx.x;
  const int b = blk >> 3, ch = blk & 7;
  float ljx = 0.0f, lja = 0.0f;

  for (int j = ch * 256 + tid; j < Nn * NTc; j += 2048) {
    int n = j / NTc, c = j - n * NTc;
    int row = b * Nn + n;
    float v = x_deq[b * (Nn * NTc) + j];
    #pragma unroll
    for (int i = 0; i < Ll; ++i) {
      float s = sn[((size_t)i * (Bc * Nn) + row) * NTc + c];
      float t = tn[((size_t)i * (Bc * Nn) + row) * NTc + c];
      v = v * s + t;
      ljx += logf(fabsf(s) + 1e-20f);
    }
    out[b * (Nn * NTc) + j] = v;
  }

  for (int j = ch * 256 + tid; j < Ee * ETc; j += 2048) {
    int e = j / ETc, c = j - e * ETc;
    int row = b * Ee + e;
    float v = adj_deq[b * (Ee * ETc) + j];
    #pragma unroll
    for (int i = 0; i < Ll; ++i) {
      float s = se[((size_t)i * (Bc * Ee) + row) * ETc + c];
      float t = te[((size_t)i * (Bc * Ee) + row) * ETc + c];
      v = v * s + t;
      lja += logf(fabsf(s) + 1e-20f);
    }
    out[Bc * Nn * NTc + b * (Ee * ETc) + j] = v;
  }

  __shared__ float red[256];
  red[tid] = ljx; __syncthreads();
  for (int st = 128; st > 0; st >>= 1) { if (tid < st) red[tid] += red[tid + st]; __syncthreads(); }
  if (tid == 0) partials[blk] = red[0];
  __syncthreads();
  red[tid] = lja; __syncthreads();
  for (int st = 128; st > 0; st >>= 1) { if (tid < st) red[tid] += red[tid + st]; __syncthreads(); }
  if (tid == 0) partials[64 + blk] = red[0];
}

__global__ void combine_lj(const float* __restrict__ partials, float* __restrict__ out)
{
  int tid = threadIdx.x;
  if (tid < Bc) {
    float sx = 0.0f, sa = 0.0f;
    #pragma unroll
    for (int ch = 0; ch < 8; ++ch) {
      sx += partials[tid * 8 + ch];
      sa += partials[64 + tid * 8 + ch];
    }
    out[Bc * Nn * NTc + Bc * Ee * ETc + tid] = sx;
    out[Bc * Nn * NTc + Bc * Ee * ETc + Bc + tid] = sa;
  }
}

extern "C" void kernel_launch(void* const* d_in, const int* in_sizes, int n_in,
                              void* d_out, int out_size, void* d_ws, size_t ws_size,
                              hipStream_t stream)
{
  const float* x       = (const float*)d_in[0];
  const float* adj     = (const float*)d_in[1];
  const float* x_deq   = (const float*)d_in[2];
  const float* adj_deq = (const float*)d_in[3];
  const void*  mn_src  = d_in[4];
  const void*  me_src  = d_in[5];
  const int*   isel    = (const int*)d_in[6];
  const float* emb_w   = (const float*)d_in[7];
  const float* gw      = (const float*)d_in[8];
  const float* gb      = (const float*)d_in[9];
  const float* nw1     = (const float*)d_in[10];
  const float* nb1     = (const float*)d_in[11];
  const float* nw2     = (const float*)d_in[12];
  const float* nb2     = (const float*)d_in[13];
  const float* ew1     = (const float*)d_in[14];
  const float* eb1     = (const float*)d_in[15];
  const float* ew2     = (const float*)d_in[16];
  const float* eb2     = (const float*)d_in[17];

  char* ws = (char*)d_ws;
  uint8_t* mn            = (uint8_t*)(ws + WS_MN);
  uint8_t* mep           = (uint8_t*)(ws + WS_MEP);
  float* h0              = (float*)(ws + WS_H0);
  unsigned short* St     = (unsigned short*)(ws + WS_ST);
  unsigned short* gwt    = (unsigned short*)(ws + WS_GWT);
  unsigned short* nwt    = (unsigned short*)(ws + WS_NWT);
  unsigned short* ewt    = (unsigned short*)(ws + WS_EWT);
  unsigned short* adjp   = (unsigned short*)(ws + WS_ADJP);
  unsigned short* gnb    = (unsigned short*)(ws + WS_GNB);
  unsigned short* gedge  = (unsigned short*)(ws + WS_GEDGE);
  float* sn              = (float*)(ws + WS_SN);
  float* tn              = (float*)(ws + WS_TN);
  float* se              = (float*)(ws + WS_SE);
  float* te              = (float*)(ws + WS_TE);
  float* partials        = (float*)(ws + WS_PART);

  const int NW_TOT = 9 * 128 * 128 + 12 * 128 * 128 + 12 * 128 * 384 + Bc * GL * 48 * 64;

  prep_masks<<<256, 256, 0, stream>>>(mn_src, me_src, mn, mep);
  prep_weights<<<(NW_TOT + 255) / 256, 256, 0, stream>>>(gw, nw1, ew1, adj, gwt, nwt, ewt, adjp);
  h0_kernel<<<(Bc * Nn * Hh + 255) / 256, 256, 0, stream>>>(x, emb_w, h0);
  s_kernel<<<(Bc * GL * Hh * 64 + 255) / 256, 256, 0, stream>>>(h0, gw, St);
  gcn_mfma_kernel<<<Bc * Rr, 512, 0, stream>>>(adjp, mn, mep, St, gwt, gb, isel, gnb, gedge);
  st_mfma_kernel<128, NTc, Bc * Nn><<<Ll * ((Bc * Nn + 31) / 32), 256, 0, stream>>>(
      gnb, nwt, nb1, nw2, nb2, sn, tn);
  st_mfma_kernel<384, ETc, Bc * Ee><<<Ll * ((Bc * Ee + 31) / 32), 256, 0, stream>>>(
      gedge, ewt, eb1, ew2, eb2, se, te);
  combine_part<<<Bc * 8, 256, 0, stream>>>(x_deq, adj_deq, sn, tn, se, te, (float*)d_out, partials);
  combine_lj<<<1, 64, 0, stream>>>(partials, (float*)d_out);
}